// Round 6
// baseline (191.768 us; speedup 1.0000x reference)
//
#include <hip/hip_runtime.h>
#include <cfloat>
#include <cmath>

#define VOCAB 8192
#define MTOT 16384
#define CDIM 256
#define KSPLIT 8
#define TAU 0.1f
#define IDX_INF 0x7fffffff

typedef __attribute__((ext_vector_type(8))) short bf16x8;
typedef __attribute__((ext_vector_type(4))) float f32x4;

#define AS1 __attribute__((address_space(1)))
#define AS3 __attribute__((address_space(3)))

__device__ __forceinline__ void gl_lds16(const void* g, void* l) {
  __builtin_amdgcn_global_load_lds((const AS1 unsigned int*)g,
                                   (AS3 unsigned int*)l, 16, 0, 0);
}

__device__ inline ushort f2bf(float f) {
  unsigned u = __float_as_uint(f);
  unsigned r = (u + 0x7fffu + ((u >> 16) & 1u)) >> 16;
  return (ushort)r;
}

// ---------------- enorm: ||e_k||^2 fp32 + exact fp64 ----------------
__global__ void vq_enorm_kernel(const float* __restrict__ emb,
                                float* __restrict__ enorm,
                                double* __restrict__ enormd) {
  __shared__ double sd[4][64];
  int tid = threadIdx.x;
  int kk = tid & 63, cg = tid >> 6;
  int k = blockIdx.x * 64 + kk;
  double s = 0.0;
  for (int c = cg * 64; c < cg * 64 + 64; ++c) {
    float v = emb[(size_t)c * VOCAB + k];
    s += (double)v * (double)v;
  }
  sd[cg][kk] = s;
  __syncthreads();
  if (cg == 0) {
    double t = sd[0][kk] + sd[1][kk] + sd[2][kk] + sd[3][kk];
    enorm[k] = (float)t;
    enormd[k] = t;
  }
}

// ---------------- transpose emb [C][K] -> embT [K][C] fp32 ----------------
__global__ void vq_prep_embT_kernel(const float* __restrict__ emb,
                                    float* __restrict__ embT) {
  __shared__ float t[32][33];
  int bc = blockIdx.x & 7;    // C/32 = 8
  int bk = blockIdx.x >> 3;   // K/32 = 256
  int lx = threadIdx.x & 31, lyq = threadIdx.x >> 5;
#pragma unroll
  for (int yy = 0; yy < 4; ++yy) {
    int y = lyq * 4 + yy;
    t[y][lx] = emb[(size_t)(bc * 32 + y) * VOCAB + bk * 32 + lx];
  }
  __syncthreads();
#pragma unroll
  for (int yy = 0; yy < 4; ++yy) {
    int y = lyq * 4 + yy;
    embT[(size_t)(bk * 32 + y) * CDIM + bc * 32 + lx] = t[lx][y];
  }
}

// ---------------- pack -2x -> bf16 pair-swizzled strips ----------------
// strip rb (128 rows): granule o: cc=o>>9, w=o&511, pair=w>>3, sswz=w&7;
// s=sswz^(pair&7); row=pair*2+(s>>2); g=s&3; dims=cc*32+g*8
__global__ void vq_pack_x_kernel(const float* __restrict__ x,
                                 ushort* __restrict__ xb) {
  int u = blockIdx.x * 256 + threadIdx.x;
  int rb = u >> 12;
  int o = u & 4095;
  int cc = o >> 9, w = o & 511;
  int pair = w >> 3, sswz = w & 7;
  int s = sswz ^ (pair & 7);
  int row = pair * 2 + (s >> 2);
  int g = s & 3;
  const float* src = x + (size_t)(rb * 128 + row) * CDIM + cc * 32 + g * 8;
  float4 v0 = *(const float4*)src;
  float4 v1 = *(const float4*)(src + 4);
  float a[8] = {v0.x, v0.y, v0.z, v0.w, v1.x, v1.y, v1.z, v1.w};
  bf16x8 h;
#pragma unroll
  for (int j = 0; j < 8; ++j) h[j] = (short)f2bf(-2.0f * a[j]);
  *(bf16x8*)(xb + (size_t)u * 8) = h;
}

// ---------------- pack embT -> bf16 pair-swizzled code chunks ----------------
// per (sp, ct, chunk): 2048 granules [wcg 4][pair 64][sswz 8]
__global__ void vq_pack_e_kernel(const float* __restrict__ embT,
                                 ushort* __restrict__ eb) {
  int u = blockIdx.x * 256 + threadIdx.x;
  int sp = u >> 15;
  int r = u & 32767;
  int ct = (r >> 14) & 1, chunk = (r >> 11) & 7;
  int o16 = r & 2047;
  int wcg = o16 >> 9, w = o16 & 511;
  int pair = w >> 3, sswz = w & 7;
  int s = sswz ^ (pair & 7);
  int cloc = pair * 2 + (s >> 2);
  int g = s & 3;
  int code = sp * 1024 + ct * 512 + wcg * 128 + cloc;
  int dims = chunk * 32 + g * 8;
  const float* src = embT + (size_t)code * CDIM + dims;
  float4 v0 = *(const float4*)src;
  float4 v1 = *(const float4*)(src + 4);
  float a[8] = {v0.x, v0.y, v0.z, v0.w, v1.x, v1.y, v1.z, v1.w};
  bf16x8 h;
#pragma unroll
  for (int j = 0; j < 8; ++j) h[j] = (short)f2bf(a[j]);
  *(bf16x8*)(eb + (size_t)u * 8) = h;
}

// ---------------- bf16 MFMA distance, 64x128 wave tile, exact fp32 stream minima ----------------
__global__ __launch_bounds__(512, 2) void vq_dist_kernel(
    const ushort* __restrict__ xb, const ushort* __restrict__ eb,
    const float* __restrict__ enorm,
    float4* __restrict__ pkd, int4* __restrict__ pki) {
  __shared__ ushort Abuf[32768];        // 64 KB: [cc 8][pair 64][slot 8] granules
  __shared__ ushort Bbuf[2][16384];     // 2x32 KB: [wcg 4][pair 64][slot 8]

  const int tid = threadIdx.x;
  const int lane = tid & 63, wid = tid >> 6;
  const int wr = wid >> 2, wc = wid & 3;     // 2 (rows) x 4 (codes) wave grid
  const int l15 = lane & 15, lg = lane >> 4;
  const int rb = blockIdx.x >> 3, sp = blockIdx.x & 7;
  const int m0 = rb * 128;
  const int spbase = sp * 1024;

  // prologue staging: full A strip (64 KB) + B chunk 0
  {
    const ushort* xs = xb + (size_t)rb * 32768;
#pragma unroll
    for (int i = 0; i < 8; ++i)
      gl_lds16(xs + (wid * 8 + i) * 512 + lane * 8, &Abuf[(wid * 8 + i) * 512]);
    const ushort* bs = eb + (size_t)sp * 262144;
#pragma unroll
    for (int i = 0; i < 4; ++i)
      gl_lds16(bs + (wid * 4 + i) * 512 + lane * 8, &Bbuf[0][(wid * 4 + i) * 512]);
  }

  // LDS read byte-offsets (pair-swizzle: pair=row>>1, s=(row&1)*4+lg, slot=s^(pair&7))
  uint offA[4], offB[8];
#pragma unroll
  for (int mf = 0; mf < 4; ++mf) {
    int row = wr * 64 + mf * 16 + l15;
    int pr = row >> 1, s = ((row & 1) << 2) | lg;
    offA[mf] = pr * 128 + ((s ^ (pr & 7)) << 4);
  }
#pragma unroll
  for (int nf = 0; nf < 8; ++nf) {
    int cl = nf * 16 + l15;
    int pr = cl >> 1, s = ((cl & 1) << 2) | lg;
    offB[nf] = wc * 8192 + pr * 128 + ((s ^ (pr & 7)) << 4);
  }

  float bv[16];
  int bi[16];
#pragma unroll
  for (int s = 0; s < 16; ++s) { bv[s] = FLT_MAX; bi[s] = IDX_INF; }

#pragma unroll
  for (int ct = 0; ct < 2; ++ct) {
    // per-ct accumulator init with ||e||^2 (distance materializes in acc)
    float e16[8];
#pragma unroll
    for (int nf = 0; nf < 8; ++nf)
      e16[nf] = enorm[spbase + ct * 512 + wc * 128 + nf * 16 + l15];
    f32x4 acc[4][8];
#pragma unroll
    for (int mf = 0; mf < 4; ++mf)
#pragma unroll
      for (int nf = 0; nf < 8; ++nf)
        acc[mf][nf] = (f32x4){e16[nf], e16[nf], e16[nf], e16[nf]};

#pragma unroll
    for (int cc = 0; cc < 8; ++cc) {
      const int step = ct * 8 + cc;
      __syncthreads();   // staged chunk `step` now resident (vmcnt drained)
      if (step < 15) {   // issue next chunk's staging; lands during compute
        const ushort* bs = eb + (size_t)sp * 262144 + (size_t)(step + 1) * 16384;
        ushort* dst = &Bbuf[(step + 1) & 1][0];
#pragma unroll
        for (int i = 0; i < 4; ++i)
          gl_lds16(bs + (wid * 4 + i) * 512 + lane * 8, dst + (wid * 4 + i) * 512);
      }
      const char* Ab = (const char*)Abuf + cc * 8192;
      const char* Bb = (const char*)&Bbuf[cc & 1][0];
      bf16x8 af[4];
#pragma unroll
      for (int mf = 0; mf < 4; ++mf) af[mf] = *(const bf16x8*)(Ab + offA[mf]);
#pragma unroll
      for (int nf = 0; nf < 8; ++nf) {
        bf16x8 bfr = *(const bf16x8*)(Bb + offB[nf]);
#pragma unroll
        for (int mf = 0; mf < 4; ++mf)
          acc[mf][nf] = __builtin_amdgcn_mfma_f32_16x16x32_bf16(af[mf], bfr, acc[mf][nf], 0, 0, 0);
      }
    }
    // fold ct's distances into per-stream exact (d, idx) minima; strict < = first occurrence
#pragma unroll
    for (int nf = 0; nf < 8; ++nf) {
      int n = spbase + ct * 512 + wc * 128 + nf * 16 + l15;
#pragma unroll
      for (int mf = 0; mf < 4; ++mf)
#pragma unroll
        for (int r = 0; r < 4; ++r) {
          float d = acc[mf][nf][r];
          int s = mf * 4 + r;
          if (d < bv[s]) { bv[s] = d; bi[s] = n; }
        }
    }
  }

  // hierarchical merge: 64 streams/row -> top-4 per (row, split)
  __syncthreads();
  float* kd = (float*)Abuf;          // 8192 floats (32 KB)
  int* ki = (int*)Abuf + 8192;       // 8192 ints (32 KB)
#pragma unroll
  for (int mf = 0; mf < 4; ++mf)
#pragma unroll
    for (int r = 0; r < 4; ++r) {
      int row = wr * 64 + mf * 16 + lg * 4 + r;
      int idx = (wc * 128 + row) * 16 + l15;
      kd[idx] = bv[mf * 4 + r];
      ki[idx] = bi[mf * 4 + r];
    }
  __syncthreads();
  float* kod = (float*)&Bbuf[0][0];          // 1024 floats
  int* koi = (int*)&Bbuf[0][0] + 1024;       // 1024 ints
  {
    int row = tid >> 2, part = tid & 3;
    const float* rd = kd + (part * 128 + row) * 16;
    const int* ri = ki + (part * 128 + row) * 16;
    float d0 = FLT_MAX, d1 = FLT_MAX;
    int i0 = IDX_INF, i1 = IDX_INF;
#pragma unroll
    for (int j = 0; j < 16; ++j) {
      float a = rd[j];
      int ai = ri[j];
      if (a < d0 || (a == d0 && ai < i0)) { d1 = d0; i1 = i0; d0 = a; i0 = ai; }
      else if (a < d1 || (a == d1 && ai < i1)) { d1 = a; i1 = ai; }
    }
    int o = (row * 4 + part) * 2;
    kod[o] = d0; kod[o + 1] = d1;
    koi[o] = i0; koi[o + 1] = i1;
  }
  __syncthreads();
  if (tid < 128) {
    const float* rd = kod + tid * 8;
    const int* ri = koi + tid * 8;
    float d[4] = {FLT_MAX, FLT_MAX, FLT_MAX, FLT_MAX};
    int ix[4] = {IDX_INF, IDX_INF, IDX_INF, IDX_INF};
#pragma unroll
    for (int j = 0; j < 8; ++j) {
      float a = rd[j];
      int ai = ri[j];
#pragma unroll
      for (int q = 0; q < 4; ++q) {
        bool lt = (a < d[q]) || (a == d[q] && ai < ix[q]);
        float td = lt ? d[q] : a;
        int ti = lt ? ix[q] : ai;
        d[q] = lt ? a : d[q];
        ix[q] = lt ? ai : ix[q];
        a = td; ai = ti;
      }
    }
    pkd[(size_t)sp * MTOT + m0 + tid] = make_float4(d[0], d[1], d[2], d[3]);
    pki[(size_t)sp * MTOT + m0 + tid] = make_int4(ix[0], ix[1], ix[2], ix[3]);
  }
}

// ---------------- merge 32 candidates + fp64 rescue + gather (1 wave / row) ----------------
__global__ void vq_gather_kernel(
    const float* __restrict__ x, const float* __restrict__ embT,
    const double* __restrict__ enormd,
    const float4* __restrict__ pkd, const int4* __restrict__ pki,
    float* __restrict__ out, int* __restrict__ counts, float* __restrict__ ssep) {
  const int wid = threadIdx.x >> 6, lane = threadIdx.x & 63;
  const int m = blockIdx.x * 4 + wid;

  const float4 xq = *(const float4*)(x + (size_t)m * CDIM + lane * 4);

  float bd = FLT_MAX, sd = FLT_MAX;
  int bidx = IDX_INF;
#pragma unroll
  for (int sp2 = 0; sp2 < KSPLIT; ++sp2) {
    float4 dv = pkd[(size_t)sp2 * MTOT + m];
    int4 iv = pki[(size_t)sp2 * MTOT + m];
    float ds[4] = {dv.x, dv.y, dv.z, dv.w};
    int is[4] = {iv.x, iv.y, iv.z, iv.w};
#pragma unroll
    for (int j = 0; j < 4; ++j) {
      float dj = ds[j];
      int ij = is[j];
      if (dj < bd || (dj == bd && ij < bidx)) { sd = bd; bd = dj; bidx = ij; }
      else sd = fminf(sd, dj);
    }
  }
  int best = bidx;
  if (sd - bd < TAU) {   // ambiguous: exact fp64 over all 32 candidates (wave-uniform)
    double bD = DBL_MAX;
    int bn = IDX_INF;
    for (int sp2 = 0; sp2 < KSPLIT; ++sp2) {
      int4 iv = pki[(size_t)sp2 * MTOT + m];
      int is[4] = {iv.x, iv.y, iv.z, iv.w};
#pragma unroll
      for (int j = 0; j < 4; ++j) {
        int cj = is[j];
        const float4 ev = *(const float4*)(embT + (size_t)cj * CDIM + lane * 4);
        double p = (double)xq.x * ev.x + (double)xq.y * ev.y
                 + (double)xq.z * ev.z + (double)xq.w * ev.w;
#pragma unroll
        for (int off = 1; off < 64; off <<= 1) p += __shfl_xor(p, off, 64);
        double dj = enormd[cj] - 2.0 * p;
        if (dj < bD || (dj == bD && cj < bn)) { bD = dj; bn = cj; }
      }
    }
    best = bn;
  }
  const float4 ev = *(const float4*)(embT + (size_t)best * CDIM + lane * 4);
  *(float4*)(out + (size_t)m * CDIM + lane * 4) = ev;
  float dx = ev.x - xq.x, dy = ev.y - xq.y, dz = ev.z - xq.z, dw = ev.w - xq.w;
  float v = dx * dx + dy * dy + dz * dz + dw * dw;
#pragma unroll
  for (int off = 32; off > 0; off >>= 1) v += __shfl_down(v, off, 64);
  if (lane == 0) {
    ssep[m] = v;
    atomicAdd(&counts[best], 1);
  }
}

// ---------------- loss + perplexity, two-stage deterministic ----------------
__global__ void vq_final1_kernel(const float* __restrict__ ssep,
                                 const int* __restrict__ counts,
                                 double* __restrict__ part) {
  __shared__ double red[256];
  const int tid = threadIdx.x, b = blockIdx.x;
  red[tid] = (double)ssep[b * 256 + tid];
  __syncthreads();
  for (int off = 128; off > 0; off >>= 1) {
    if (tid < off) red[tid] += red[tid + off];
    __syncthreads();
  }
  if (tid == 0) part[b] = red[0];
  __syncthreads();
  double e = 0.0;
  if (tid < 128) {
    double p = (double)counts[b * 128 + tid] / (double)MTOT;
    e = p * log(p + 1e-10);
  }
  red[tid] = e;
  __syncthreads();
  for (int off = 128; off > 0; off >>= 1) {
    if (tid < off) red[tid] += red[tid + off];
    __syncthreads();
  }
  if (tid == 0) part[64 + b] = red[0];
}

__global__ void vq_final2_kernel(const double* __restrict__ part,
                                 float* __restrict__ out) {
  const int lane = threadIdx.x;   // 64 threads
  double s = part[lane], e = part[64 + lane];
#pragma unroll
  for (int off = 32; off > 0; off >>= 1) {
    s += __shfl_down(s, off, 64);
    e += __shfl_down(e, off, 64);
  }
  if (lane == 0) {
    out[(size_t)MTOT * CDIM] = (float)(1.25 * s / (double)((size_t)MTOT * CDIM));
    out[(size_t)MTOT * CDIM + 1] = (float)exp(-e);
  }
}

extern "C" void kernel_launch(void* const* d_in, const int* in_sizes, int n_in,
                              void* d_out, int out_size, void* d_ws, size_t ws_size,
                              hipStream_t stream) {
  const float* x = (const float*)d_in[0];
  const float* emb = (const float*)d_in[1];
  float* out = (float*)d_out;
  char* ws = (char*)d_ws;

  // workspace layout (bytes)
  double* enormd = (double*)(ws);                 //        0: 65536
  float* enorm   = (float*)(ws + 65536);          //    65536: 32768
  float4* pkd    = (float4*)(ws + 98304);         //    98304: 2097152
  int4* pki      = (int4*)(ws + 2195456);         //  2195456: 2097152
  int* counts    = (int*)(ws + 4292608);          //  4292608: 32768
  float* ssep    = (float*)(ws + 4325376);        //  4325376: 65536
  double* part   = (double*)(ws + 4390912);       //  4390912: 1024
  float* embT    = (float*)(ws + 4391936);        //  4391936: 8388608
  ushort* xb     = (ushort*)(ws + 12780544);      // 12780544: 8388608
  ushort* eb     = (ushort*)(ws + 21169152);      // 21169152: 4194304
  // total 25363456 bytes (< 35 MB proven available in rounds 1-5)

  hipMemsetAsync(counts, 0, VOCAB * sizeof(int), stream);
  vq_enorm_kernel<<<VOCAB / 64, 256, 0, stream>>>(emb, enorm, enormd);
  vq_prep_embT_kernel<<<(VOCAB / 32) * (CDIM / 32), 256, 0, stream>>>(emb, embT);
  vq_pack_e_kernel<<<(VOCAB * CDIM / 8) / 256, 256, 0, stream>>>(embT, eb);
  vq_pack_x_kernel<<<(MTOT * CDIM / 8) / 256, 256, 0, stream>>>(x, xb);
  vq_dist_kernel<<<(MTOT / 128) * KSPLIT, 512, 0, stream>>>(xb, eb, enorm, pkd, pki);
  vq_gather_kernel<<<MTOT / 4, 256, 0, stream>>>(x, embT, enormd, pkd, pki,
                                                 out, counts, ssep);
  vq_final1_kernel<<<64, 256, 0, stream>>>(ssep, counts, part);
  vq_final2_kernel<<<1, 64, 0, stream>>>(part, out);
}